// Round 1
// baseline (158.313 us; speedup 1.0000x reference)
//
#include <hip/hip_runtime.h>

typedef __bf16 bf16;
typedef __bf16 bf16x8 __attribute__((ext_vector_type(8)));
typedef __bf16 bf16x4 __attribute__((ext_vector_type(4)));
typedef float  f32x4  __attribute__((ext_vector_type(4)));

constexpr int DIM_  = 1024;
constexpr int NH    = 16;
constexpr int CHD   = 32;     // current head dim
constexpr int CDIM  = 512;    // NH * CHD
constexpr int CQ    = 1536;   // 3 * CDIM
constexpr int NSEQ  = 2048;
constexpr int M_    = 4096;   // B * N
constexpr float ATT_SCALE = 0.17677669529663687f; // (64^-0.5)/sqrt(0.5)

// ---------------- casts ----------------
__global__ void cast_kernel(const float* __restrict__ src, bf16* __restrict__ dst, int n4) {
    int stride = gridDim.x * blockDim.x;
    for (int i = blockIdx.x * blockDim.x + threadIdx.x; i < n4; i += stride) {
        float4 v = reinterpret_cast<const float4*>(src)[i];
        bf16x4 o = { (bf16)v.x, (bf16)v.y, (bf16)v.z, (bf16)v.w };
        reinterpret_cast<bf16x4*>(dst)[i] = o;
    }
}

// w_proj is 1024x1024 row-major; we need bf16 [1024][512] = first 512 cols of each row
__global__ void cast_wproj_kernel(const float* __restrict__ w, bf16* __restrict__ dst) {
    int i = blockIdx.x * blockDim.x + threadIdx.x;   // 1024*128 exactly
    int c = i >> 7, j4 = i & 127;
    float4 v = reinterpret_cast<const float4*>(w + c * DIM_)[j4];
    bf16x4 o = { (bf16)v.x, (bf16)v.y, (bf16)v.z, (bf16)v.w };
    reinterpret_cast<bf16x4*>(dst + c * CDIM)[j4] = o;
}

// ---------------- repack qkv -> per-head q, k, v^T ----------------
__global__ void repack_kernel(const bf16* __restrict__ qkv, bf16* __restrict__ qb,
                              bf16* __restrict__ kb, bf16* __restrict__ vt) {
    int i = blockIdx.x * blockDim.x + threadIdx.x;   // M_*CQ exactly
    int m = i / CQ;
    int n = i - m * CQ;
    int which = n >> 9;        // 0=q 1=k 2=v
    int rem = n & 511;
    int h = rem >> 5, d = rem & 31;
    int b = m >> 11, pos = m & 2047;
    int bh = b * NH + h;
    bf16 v = qkv[i];
    if (which == 0)      qb[(bh * NSEQ + pos) * CHD + d] = v;
    else if (which == 1) kb[(bh * NSEQ + pos) * CHD + d] = v;
    else                 vt[(bh * CHD + d) * NSEQ + pos] = v;
}

// ---------------- NT GEMM: C[m][n] = sum_k A[m][k] * B[n][k] ----------------
// 128x128 tile, BK=32, 4 waves (2x2), each wave 64x64 (4x4 MFMA frags).
template<int KDIM, int NSTR, bool PROJ>
__launch_bounds__(256)
__global__ void gemm_nt(const bf16* __restrict__ A, const bf16* __restrict__ Bm,
                        bf16* __restrict__ Cb, float* __restrict__ Cf,
                        const float* __restrict__ bias) {
    __shared__ __align__(16) bf16 As[128 * 32];
    __shared__ __align__(16) bf16 Bs[128 * 32];
    const int tid = threadIdx.x;
    const int w = tid >> 6, lane = tid & 63;
    const int m0 = blockIdx.x * 128, n0 = blockIdx.y * 128;
    const int wr = (w >> 1) * 64, wc = (w & 1) * 64;
    const int lrow = lane >> 2, lk = (lane & 3) * 8;       // staging map
    const int cl = lane & 15, gk8 = (lane >> 4) * 8;       // fragment map

    const bf16* ga = A  + (m0 + w * 16 + lrow) * KDIM + lk;
    const bf16* gb = Bm + (n0 + w * 16 + lrow) * KDIM + lk;

    f32x4 acc[4][4] = {};

    for (int k0 = 0; k0 < KDIM; k0 += 32) {
        __builtin_amdgcn_global_load_lds((const __attribute__((address_space(1))) void*)(ga + k0),
                                         (__attribute__((address_space(3))) void*)(As + w * 512), 16, 0, 0);
        __builtin_amdgcn_global_load_lds((const __attribute__((address_space(1))) void*)(ga + 64 * KDIM + k0),
                                         (__attribute__((address_space(3))) void*)(As + 2048 + w * 512), 16, 0, 0);
        __builtin_amdgcn_global_load_lds((const __attribute__((address_space(1))) void*)(gb + k0),
                                         (__attribute__((address_space(3))) void*)(Bs + w * 512), 16, 0, 0);
        __builtin_amdgcn_global_load_lds((const __attribute__((address_space(1))) void*)(gb + 64 * KDIM + k0),
                                         (__attribute__((address_space(3))) void*)(Bs + 2048 + w * 512), 16, 0, 0);
        __syncthreads();   // compiler emits vmcnt(0) drain before barrier

        bf16x8 af[4], bfr[4];
#pragma unroll
        for (int i = 0; i < 4; ++i)
            af[i]  = *reinterpret_cast<const bf16x8*>(As + (wr + i * 16 + cl) * 32 + gk8);
#pragma unroll
        for (int j = 0; j < 4; ++j)
            bfr[j] = *reinterpret_cast<const bf16x8*>(Bs + (wc + j * 16 + cl) * 32 + gk8);
#pragma unroll
        for (int i = 0; i < 4; ++i)
#pragma unroll
            for (int j = 0; j < 4; ++j)
                acc[i][j] = __builtin_amdgcn_mfma_f32_16x16x32_bf16(af[i], bfr[j], acc[i][j], 0, 0, 0);
        __syncthreads();
    }

    const int rg = (lane >> 4) * 4;   // D layout: row=(l>>4)*4+r, col=l&15
#pragma unroll
    for (int i = 0; i < 4; ++i) {
#pragma unroll
        for (int j = 0; j < 4; ++j) {
            const int row = m0 + wr + i * 16 + rg;
            const int col = n0 + wc + j * 16 + cl;
            if constexpr (PROJ) {
                const float bv = bias[col];
#pragma unroll
                for (int r = 0; r < 4; ++r)
                    Cf[(row + r) * NSTR + col] = acc[i][j][r] + bv;
            } else {
#pragma unroll
                for (int r = 0; r < 4; ++r)
                    Cb[(row + r) * NSTR + col] = (bf16)acc[i][j][r];
            }
        }
    }
}

// ---------------- flash attention: one head per blockIdx.y, 64 q-rows per block ----------------
__launch_bounds__(256)
__global__ void flash_kernel(const bf16* __restrict__ qb, const bf16* __restrict__ kb,
                             const bf16* __restrict__ vt, bf16* __restrict__ ob) {
    __shared__ __align__(16) bf16 Pw[4][16][72];   // per-wave P staging, padded stride
    const int tid = threadIdx.x;
    const int w = tid >> 6, lane = tid & 63;
    const int head = blockIdx.y;
    const int q0 = blockIdx.x * 64 + w * 16;
    const bf16* Q = qb + head * (NSEQ * CHD);
    const bf16* K = kb + head * (NSEQ * CHD);
    const bf16* V = vt + head * (CHD * NSEQ);      // V^T: [d][n]
    const int cl = lane & 15, gk = lane >> 4;

    const bf16x8 qf = *reinterpret_cast<const bf16x8*>(Q + (q0 + cl) * CHD + gk * 8);
    f32x4 o0 = {}, o1 = {};
    float mrun[4] = {-1e30f, -1e30f, -1e30f, -1e30f};
    float lrun[4] = {0.f, 0.f, 0.f, 0.f};
    const f32x4 zero = {};

    for (int kv0 = 0; kv0 < NSEQ; kv0 += 64) {
        f32x4 s[4];
#pragma unroll
        for (int fc = 0; fc < 4; ++fc) {
            const bf16x8 kf = *reinterpret_cast<const bf16x8*>(K + (kv0 + fc * 16 + cl) * CHD + gk * 8);
            s[fc] = __builtin_amdgcn_mfma_f32_16x16x32_bf16(qf, kf, zero, 0, 0, 0);
            s[fc] *= ATT_SCALE;
        }
#pragma unroll
        for (int r = 0; r < 4; ++r) {
            float mx = fmaxf(fmaxf(s[0][r], s[1][r]), fmaxf(s[2][r], s[3][r]));
            mx = fmaxf(mx, __shfl_xor(mx, 1));
            mx = fmaxf(mx, __shfl_xor(mx, 2));
            mx = fmaxf(mx, __shfl_xor(mx, 4));
            mx = fmaxf(mx, __shfl_xor(mx, 8));
            const float mnew = fmaxf(mrun[r], mx);
            const float al = __expf(mrun[r] - mnew);
            mrun[r] = mnew;
            float rs = 0.f;
#pragma unroll
            for (int fc = 0; fc < 4; ++fc) {
                const float p = __expf(s[fc][r] - mnew);
                s[fc][r] = p;
                rs += p;
            }
            rs += __shfl_xor(rs, 1);
            rs += __shfl_xor(rs, 2);
            rs += __shfl_xor(rs, 4);
            rs += __shfl_xor(rs, 8);
            lrun[r] = lrun[r] * al + rs;
            o0[r] *= al;
            o1[r] *= al;
        }
        // stage P (16x64) to LDS for the transpose into PV A-fragments
#pragma unroll
        for (int fc = 0; fc < 4; ++fc)
#pragma unroll
            for (int r = 0; r < 4; ++r)
                Pw[w][gk * 4 + r][fc * 16 + cl] = (bf16)s[fc][r];
        asm volatile("s_waitcnt lgkmcnt(0)" ::: "memory");
#pragma unroll
        for (int h = 0; h < 2; ++h) {
            const bf16x8 pa = *reinterpret_cast<const bf16x8*>(&Pw[w][cl][h * 32 + gk * 8]);
            const bf16x8 v0 = *reinterpret_cast<const bf16x8*>(V + cl * NSEQ + kv0 + h * 32 + gk * 8);
            const bf16x8 v1 = *reinterpret_cast<const bf16x8*>(V + (16 + cl) * NSEQ + kv0 + h * 32 + gk * 8);
            o0 = __builtin_amdgcn_mfma_f32_16x16x32_bf16(pa, v0, o0, 0, 0, 0);
            o1 = __builtin_amdgcn_mfma_f32_16x16x32_bf16(pa, v1, o1, 0, 0, 0);
        }
    }

    const int b = head >> 4, hh = head & 15;
    const int mg = b * NSEQ + q0 + gk * 4;
    const int colb = hh * CHD;
#pragma unroll
    for (int r = 0; r < 4; ++r) {
        const float inv = 1.f / lrun[r];
        ob[(mg + r) * CDIM + colb + cl]      = (bf16)(o0[r] * inv);
        ob[(mg + r) * CDIM + colb + 16 + cl] = (bf16)(o1[r] * inv);
    }
}

// ---------------- launch ----------------
extern "C" void kernel_launch(void* const* d_in, const int* in_sizes, int n_in,
                              void* d_out, int out_size, void* d_ws, size_t ws_size,
                              hipStream_t stream) {
    const float* x      = (const float*)d_in[0];
    const float* w_qkv  = (const float*)d_in[1];
    const float* w_proj = (const float*)d_in[2];
    const float* b_proj = (const float*)d_in[3];
    float* out = (float*)d_out;

    char* ws = (char*)d_ws;
    bf16* xb  = (bf16*)(ws);                         // 4096x1024      (8 MiB)
    bf16* wqb = (bf16*)(ws + 8388608);               // 1536x1024      (3 MiB)
    bf16* wpb = (bf16*)(ws + 11534336);              // 1024x512       (1 MiB)
    bf16* qkv = (bf16*)(ws + 12582912);              // 4096x1536      (12 MiB)
    bf16* qb  = (bf16*)(ws + 25165824);              // 32x2048x32     (4 MiB)
    bf16* kb  = (bf16*)(ws + 29360128);              // 32x2048x32     (4 MiB)
    bf16* vt  = (bf16*)(ws + 33554432);              // 32x32x2048     (4 MiB)
    bf16* ob  = (bf16*)(ws + 37748736);              // 4096x512       (4 MiB)

    cast_kernel<<<2048, 256, 0, stream>>>(x, xb, (M_ * DIM_) / 4);
    cast_kernel<<<1024, 256, 0, stream>>>(w_qkv, wqb, (CQ * DIM_) / 4);
    cast_wproj_kernel<<<512, 256, 0, stream>>>(w_proj, wpb);

    gemm_nt<DIM_, CQ, false><<<dim3(32, 12), 256, 0, stream>>>(xb, wqb, qkv, nullptr, nullptr);

    repack_kernel<<<(M_ * CQ) / 256, 256, 0, stream>>>(qkv, qb, kb, vt);

    flash_kernel<<<dim3(NSEQ / 64, 32), 256, 0, stream>>>(qb, kb, vt, ob);

    gemm_nt<CDIM, DIM_, true><<<dim3(32, 8), 256, 0, stream>>>(ob, wpb, nullptr, out, b_proj);
}